// Round 26
// baseline (76.443 us; speedup 1.0000x reference)
//
#include <hip/hip_runtime.h>
#include <hip/hip_bf16.h>

typedef __bf16 bf16x8 __attribute__((ext_vector_type(8)));
typedef float f32x4 __attribute__((ext_vector_type(4)));
typedef unsigned short u16x8 __attribute__((ext_vector_type(8)));

#define NB 8
#define NT 2048
#define NC 1024
#define NH 64

__device__ __forceinline__ unsigned short bfbits(float f) {
    return __builtin_bit_cast(unsigned short, (__bf16)f);
}

__device__ __forceinline__ void gl_lds16(const void* g, void* l) {
    __builtin_amdgcn_global_load_lds(
        (const __attribute__((address_space(1))) void*)g,
        (__attribute__((address_space(3))) void*)l, 16, 0, 0);
}
__device__ __forceinline__ void gl_lds16_nt(const void* g, void* l) {
    __builtin_amdgcn_global_load_lds(
        (const __attribute__((address_space(1))) void*)g,
        (__attribute__((address_space(3))) void*)l, 16, 0, 2);   // aux=2: NT
}

// ---------------- kernel 1: W -> W^T (bf16) ----------------
__global__ __launch_bounds__(256) void wt_kernel(const float* __restrict__ Wq,
                                                 const float* __restrict__ Wk,
                                                 const float* __restrict__ Wv,
                                                 unsigned short* __restrict__ Wt) {
    int idx = blockIdx.x * 256 + threadIdx.x;
    int n = idx >> 16;
    int r = idx & 65535;
    int c = r >> 6;
    int h = r & 63;
    const float* W = (n == 0) ? Wq : ((n == 1) ? Wk : Wv);
    float x = W[c * 64 + h];
    Wt[(n << 16) + h * 1024 + c] = bfbits(x);
}

// ---------------- kernel 2: pipelined gl_lds QKV projection + NT on X (R20, keep) ----------------
__global__ __launch_bounds__(256, 3) void proj_kernel(const float* __restrict__ Xv,
                                                      const float* __restrict__ Xk,
                                                      const float* __restrict__ Xq,
                                                      const unsigned short* __restrict__ Wt,
                                                      unsigned short* __restrict__ Q,
                                                      unsigned short* __restrict__ K,
                                                      unsigned short* __restrict__ VT) {
    __shared__ __align__(16) char Xs[2][16384];
    __shared__ __align__(16) char Ws[2][8192];

    int type = blockIdx.x >> 8;          // 0=Q,1=K,2=V
    int mt   = blockIdx.x & 255;
    int row0 = mt << 6;
    int phase = mt & 15;                 // k-chunk rotation (stagger)
    const float* X = (type == 0) ? Xq : ((type == 1) ? Xk : Xv);

    int tid  = threadIdx.x;
    int w    = tid >> 6;
    int lane = tid & 63;
    int lo = lane & 15, hi = lane >> 4;
    int swz = (lo & 7) << 4;

    const char* Xbase = (const char*)X + (size_t)row0 * 4096;
    const char* Wbase = (const char*)(Wt + (type << 16));

    int xr_l = lane >> 4;
    int xc_l = (lane & 15) * 16;
    int wr_l = lane >> 3;
    int wc_l = (lane & 7) * 16;

    f32x4 acc[4];
#pragma unroll
    for (int ct = 0; ct < 4; ++ct) acc[ct] = 0.f;

    auto stage = [&](int kc, int buf) {
#pragma unroll
        for (int i = 0; i < 4; ++i) {
            int g = w * 4 + i;
            int r = g * 4 + xr_l;
            gl_lds16_nt(Xbase + (size_t)r * 4096 + kc * 256 + (xc_l ^ ((r & 7) << 4)),
                        Xs[buf] + g * 1024);
        }
#pragma unroll
        for (int i = 0; i < 2; ++i) {
            int g = w * 2 + i;
            int h = g * 8 + wr_l;
            gl_lds16(Wbase + (size_t)h * 2048 + kc * 128 + (wc_l ^ ((h & 7) << 4)),
                     Ws[buf] + g * 1024);
        }
    };

    auto compute = [&](int buf) {
        const char* xrow = Xs[buf] + (w * 16 + lo) * 256;
        const char* wb   = Ws[buf];
#pragma unroll
        for (int ks = 0; ks < 2; ++ks) {
            f32x4 a0 = *(const f32x4*)(xrow + ((ks * 128 + hi * 32) ^ swz));
            f32x4 a1 = *(const f32x4*)(xrow + ((ks * 128 + hi * 32 + 16) ^ swz));
            bf16x8 af;
            af[0] = (__bf16)a0[0]; af[1] = (__bf16)a0[1]; af[2] = (__bf16)a0[2]; af[3] = (__bf16)a0[3];
            af[4] = (__bf16)a1[0]; af[5] = (__bf16)a1[1]; af[6] = (__bf16)a1[2]; af[7] = (__bf16)a1[3];
#pragma unroll
            for (int ct = 0; ct < 4; ++ct) {
                bf16x8 bf = *(const bf16x8*)(wb + (ct * 16 + lo) * 128 + ((ks * 64 + hi * 16) ^ swz));
                acc[ct] = __builtin_amdgcn_mfma_f32_16x16x32_bf16(af, bf, acc[ct], 0, 0, 0);
            }
        }
    };

    stage(phase, 0);
    stage((1 + phase) & 15, 1);

    for (int c = 0; c < 16; ++c) {
        int buf = c & 1;
        if (c < 15) asm volatile("s_waitcnt vmcnt(6)" ::: "memory");
        else        asm volatile("s_waitcnt vmcnt(0)" ::: "memory");
        __builtin_amdgcn_s_barrier();
        compute(buf);
        if (c + 2 < 16) {
            __builtin_amdgcn_s_barrier();
            stage((c + 2 + phase) & 15, buf);
        }
    }

    if (type < 2) {
        unsigned short* O = (type == 0) ? Q : K;
#pragma unroll
        for (int ct = 0; ct < 4; ++ct)
#pragma unroll
            for (int r = 0; r < 4; ++r) {
                int row = row0 + w * 16 + hi * 4 + r;
                int h = lo + 16 * ct;
                O[(size_t)row * NH + h] = bfbits(acc[ct][r]);
            }
    } else {
        int trow = row0 + w * 16 + hi * 4;
        int b = trow >> 11;
        int t = trow & 2047;
#pragma unroll
        for (int ct = 0; ct < 4; ++ct) {
            int h = lo + 16 * ct;
            ushort4 pk;
            pk.x = bfbits(acc[ct][0]);
            pk.y = bfbits(acc[ct][1]);
            pk.z = bfbits(acc[ct][2]);
            pk.w = bfbits(acc[ct][3]);
            *(ushort4*)(VT + (size_t)(b * NH + h) * NT + t) = pk;
        }
    }
}

// ---------------- kernel 3: causal flash attention (dual-stream ILP) ----------------
// Two complementary q-tiles (j, 127-j) interleaved at chunk granularity in ONE
// loop: 2 independent latency chains per wave at unchanged occupancy (256,2).
// Fixed-shift softmax, swizzled per-stream P-LDS, K-prefetch after QK^T use.
#define LOADK(c_, kn_)                                                                   \
    {                                                                                    \
        const unsigned short* kp_ = K + (size_t)(b * NT + ((c_) << 6) + lo) * NH + hi * 8; \
        _Pragma("unroll")                                                                \
        for (int g = 0; g < 4; ++g) {                                                    \
            kn_[2 * g]     = *(const bf16x8*)(kp_ + g * 16 * NH);                        \
            kn_[2 * g + 1] = *(const bf16x8*)(kp_ + g * 16 * NH + 32);                   \
        }                                                                                \
    }

#define CHUNK(q0_, c_, c1_, kn_, qf0_, qf1_, acc_, l_, plb_)                             \
    {                                                                                    \
        int s0_ = (c_) << 6;                                                             \
        const unsigned short* vb_ = VT + (size_t)(b * NH + lo) * NT + s0_ + hi * 8;      \
        bf16x8 v0_ = *(const bf16x8*)(vb_);                                              \
        bf16x8 v1_ = *(const bf16x8*)(vb_ + 16 * NT);                                    \
        bf16x8 v2_ = *(const bf16x8*)(vb_ + 32 * NT);                                    \
        bf16x8 v3_ = *(const bf16x8*)(vb_ + 48 * NT);                                    \
        bf16x8 v4_ = *(const bf16x8*)(vb_ + 32);                                         \
        bf16x8 v5_ = *(const bf16x8*)(vb_ + 16 * NT + 32);                               \
        bf16x8 v6_ = *(const bf16x8*)(vb_ + 32 * NT + 32);                               \
        bf16x8 v7_ = *(const bf16x8*)(vb_ + 48 * NT + 32);                               \
        f32x4 S_[4];                                                                     \
        _Pragma("unroll")                                                                \
        for (int t = 0; t < 4; ++t) {                                                    \
            f32x4 s_ = 0.f;                                                              \
            s_ = __builtin_amdgcn_mfma_f32_16x16x32_bf16(qf0_, kn_[2 * t], s_, 0, 0, 0); \
            s_ = __builtin_amdgcn_mfma_f32_16x16x32_bf16(qf1_, kn_[2 * t + 1], s_, 0, 0, 0); \
            S_[t] = s_;                                                                  \
        }                                                                                \
        if ((c_) + 1 < (c1_)) LOADK((c_) + 1, kn_);  /* kn consumed; overwrite ok */     \
        _Pragma("unroll")                                                                \
        for (int r = 0; r < 4; ++r) {                                                    \
            int qi_ = (q0_) + hi * 4 + r;                                                \
            int ql_ = hi * 4 + r;                                                        \
            int sw_ = (ql_ & 7) << 4;                                                    \
            float ps_ = 0.f;                                                             \
            _Pragma("unroll")                                                            \
            for (int t = 0; t < 4; ++t) {                                                \
                int sk_ = s0_ + t * 16 + lo;                                             \
                float p_ = (sk_ <= qi_) ? exp2f(S_[t][r] - 32.f) : 0.f;                  \
                ps_ += p_;                                                               \
                int byte_ = ql_ * 128 + ((((t * 16 + lo) * 2)) ^ sw_);                   \
                *(unsigned short*)((plb_) + byte_) = bfbits(p_);                         \
            }                                                                            \
            l_[r] += ps_;                                                                \
        }                                                                                \
        int rsw_ = (lo & 7) << 4;                                                        \
        bf16x8 pa0_ = *(const bf16x8*)((plb_) + lo * 128 + ((hi * 16) ^ rsw_));          \
        bf16x8 pa1_ = *(const bf16x8*)((plb_) + lo * 128 + (((4 + hi) * 16) ^ rsw_));    \
        acc_[0] = __builtin_amdgcn_mfma_f32_16x16x32_bf16(pa0_, v0_, acc_[0], 0, 0, 0);  \
        acc_[1] = __builtin_amdgcn_mfma_f32_16x16x32_bf16(pa0_, v1_, acc_[1], 0, 0, 0);  \
        acc_[2] = __builtin_amdgcn_mfma_f32_16x16x32_bf16(pa0_, v2_, acc_[2], 0, 0, 0);  \
        acc_[3] = __builtin_amdgcn_mfma_f32_16x16x32_bf16(pa0_, v3_, acc_[3], 0, 0, 0);  \
        acc_[0] = __builtin_amdgcn_mfma_f32_16x16x32_bf16(pa1_, v4_, acc_[0], 0, 0, 0);  \
        acc_[1] = __builtin_amdgcn_mfma_f32_16x16x32_bf16(pa1_, v5_, acc_[1], 0, 0, 0);  \
        acc_[2] = __builtin_amdgcn_mfma_f32_16x16x32_bf16(pa1_, v6_, acc_[2], 0, 0, 0);  \
        acc_[3] = __builtin_amdgcn_mfma_f32_16x16x32_bf16(pa1_, v7_, acc_[3], 0, 0, 0);  \
        ++(c_);                                                                          \
    }

__global__ __launch_bounds__(256, 2) void attn_kernel(const unsigned short* __restrict__ Q,
                                                      const unsigned short* __restrict__ K,
                                                      const unsigned short* __restrict__ VT,
                                                      float* __restrict__ out) {
    __shared__ __align__(16) unsigned short p_lds[8 * 1024];   // per-wave 2 streams x 2KB
    __shared__ __align__(16) float acc_lds[4 * 16 * 64];
    __shared__ float l_lds[4][16];

    int b = blockIdx.x & 7;               // XCD-pinned batch
    int j = blockIdx.x >> 3;              // 0..63 pair index
    int w    = threadIdx.x >> 6;
    int lane = threadIdx.x & 63;
    int lo = lane & 15, hi = lane >> 4;

    const float SC = 0.03125f * 1.44269504088896340736f;  // C^-0.5 * log2(e)
    char* plbA = (char*)p_lds + w * 4096;
    char* plbB = plbA + 2048;

    int q0A = j << 4;
    int q0B = (127 - j) << 4;

    bf16x8 qA0, qA1, qB0, qB1;
    {
        const unsigned short* qa = Q + (size_t)(b * NT + q0A + lo) * NH + hi * 8;
        const unsigned short* qb2 = Q + (size_t)(b * NT + q0B + lo) * NH + hi * 8;
        bf16x8 ra0 = *(const bf16x8*)(qa);
        bf16x8 ra1 = *(const bf16x8*)(qa + 32);
        bf16x8 rb0 = *(const bf16x8*)(qb2);
        bf16x8 rb1 = *(const bf16x8*)(qb2 + 32);
#pragma unroll
        for (int jj = 0; jj < 8; ++jj) {
            qA0[jj] = (__bf16)((float)ra0[jj] * SC);
            qA1[jj] = (__bf16)((float)ra1[jj] * SC);
            qB0[jj] = (__bf16)((float)rb0[jj] * SC);
            qB1[jj] = (__bf16)((float)rb1[jj] * SC);
        }
    }

    int CtA = (q0A + 79) >> 6;
    int CtB = (q0B + 79) >> 6;
    int cA = (CtA * w) >> 2, c1A = (CtA * (w + 1)) >> 2;
    int cB = (CtB * w) >> 2, c1B = (CtB * (w + 1)) >> 2;

    float lA[4], lB[4];
    f32x4 accA[4], accB[4];
#pragma unroll
    for (int r = 0; r < 4; ++r) { lA[r] = 0.f; lB[r] = 0.f; }
#pragma unroll
    for (int ct = 0; ct < 4; ++ct) { accA[ct] = 0.f; accB[ct] = 0.f; }

    bf16x8 knA[8], knB[8];
    if (cA < c1A) LOADK(cA, knA);
    if (cB < c1B) LOADK(cB, knB);

    // dual-stream main loop: two independent chains per wave
    while (cA < c1A || cB < c1B) {
        if (cA < c1A) CHUNK(q0A, cA, c1A, knA, qA0, qA1, accA, lA, plbA);
        if (cB < c1B) CHUNK(q0B, cB, c1B, knB, qB0, qB1, accB, lB, plbB);
    }

    // one-time 16-lane reductions
#pragma unroll
    for (int d = 1; d < 16; d <<= 1)
#pragma unroll
        for (int r = 0; r < 4; ++r) {
            lA[r] += __shfl_xor(lA[r], d, 16);
            lB[r] += __shfl_xor(lB[r], d, 16);
        }

    // ---- merge stream A ----
#pragma unroll
    for (int r = 0; r < 4; ++r) {
        int ql = hi * 4 + r;
#pragma unroll
        for (int ct = 0; ct < 4; ++ct)
            acc_lds[(w * 16 + ql) * 64 + lo + 16 * ct] = accA[ct][r];
    }
    if (lo == 0) {
#pragma unroll
        for (int r = 0; r < 4; ++r)
            l_lds[w][hi * 4 + r] = lA[r];
    }
    __syncthreads();
    {
        int q  = threadIdx.x >> 4;
        int h0 = (threadIdx.x & 15) << 2;
        float L = l_lds[0][q] + l_lds[1][q] + l_lds[2][q] + l_lds[3][q];
        float ox = 0.f, oy = 0.f, oz = 0.f, ow = 0.f;
#pragma unroll
        for (int ww = 0; ww < 4; ++ww) {
            const float* p = acc_lds + (ww * 16 + q) * 64 + h0;
            ox += p[0]; oy += p[1]; oz += p[2]; ow += p[3];
        }
        float inv = 1.0f / L;
        *(float4*)(out + (size_t)(b * NT + q0A + q) * NH + h0) =
            make_float4(ox * inv, oy * inv, oz * inv, ow * inv);
    }
    __syncthreads();

    // ---- merge stream B ----
#pragma unroll
    for (int r = 0; r < 4; ++r) {
        int ql = hi * 4 + r;
#pragma unroll
        for (int ct = 0; ct < 4; ++ct)
            acc_lds[(w * 16 + ql) * 64 + lo + 16 * ct] = accB[ct][r];
    }
    if (lo == 0) {
#pragma unroll
        for (int r = 0; r < 4; ++r)
            l_lds[w][hi * 4 + r] = lB[r];
    }
    __syncthreads();
    {
        int q  = threadIdx.x >> 4;
        int h0 = (threadIdx.x & 15) << 2;
        float L = l_lds[0][q] + l_lds[1][q] + l_lds[2][q] + l_lds[3][q];
        float ox = 0.f, oy = 0.f, oz = 0.f, ow = 0.f;
#pragma unroll
        for (int ww = 0; ww < 4; ++ww) {
            const float* p = acc_lds + (ww * 16 + q) * 64 + h0;
            ox += p[0]; oy += p[1]; oz += p[2]; ow += p[3];
        }
        float inv = 1.0f / L;
        *(float4*)(out + (size_t)(b * NT + q0B + q) * NH + h0) =
            make_float4(ox * inv, oy * inv, oz * inv, ow * inv);
    }
}

extern "C" void kernel_launch(void* const* d_in, const int* in_sizes, int n_in,
                              void* d_out, int out_size, void* d_ws, size_t ws_size,
                              hipStream_t stream) {
    const float* values  = (const float*)d_in[0];
    const float* keys    = (const float*)d_in[1];
    const float* queries = (const float*)d_in[2];
    const float* Wk = (const float*)d_in[3];
    const float* Wq = (const float*)d_in[4];
    const float* Wv = (const float*)d_in[5];
    float* out = (float*)d_out;

    unsigned short* Wt = (unsigned short*)d_ws;        // 196608 ushorts
    unsigned short* Qb = Wt + 196608;                  // Q,K,VT: 3x1048576 ushorts
    unsigned short* Kb = Qb + 1048576;
    unsigned short* VT = Kb + 1048576;

    wt_kernel<<<768, 256, 0, stream>>>(Wq, Wk, Wv, Wt);
    proj_kernel<<<768, 256, 0, stream>>>(values, keys, queries, Wt, Qb, Kb, VT);
    attn_kernel<<<512, 256, 0, stream>>>(Qb, Kb, VT, out);
}